// Round 15
// baseline (330.544 us; speedup 1.0000x reference)
//
#include <hip/hip_runtime.h>
#include <hip/hip_bf16.h>

// out[b,e] = m[c,e] + sum_d z[b,d] * L[c,e,d],  c = components[b]
// v15: CONTIGUOUS-L restructure. All 14 prior rounds read L as 128-256B
// granules at 8KB stride -> measured ~2 TB/s (v14: 1.95), and 168MB/2.0 =
// 84us = the invariant 86-104us every structure converged to. Fill proves
// 6.85 TB/s for contiguous traffic. Fix: block = (k, 16-ROW STRIPE of L);
// B-panel = 16 rows x 8KB = 128KB CONTIGUOUS HBM, staged once to 64KB LDS
// as bf16 (coalesced 4KB/instr, granule-swizzle for conflict-free reads);
// then a BARRIER-FREE K-loop: B read-only from LDS, A direct from the
// proven L2-resident zb image (v9 addressing, depth-2 reg prefetch).
// 1280 blocks (2/CU), XCD-swizzled (zb slice L2-local per XCD). L read
// exactly once at streaming pattern. zgather/build_map/zb image/C-layout
// epilogue proven-verbatim from v6-v14.

#define DDIM  2048
#define BSAMP 1024
#define KCOMP 10
#define MPAD  160                      // max n_k pad; Binom(1024,0.1)+6sigma
#define BK    32                       // d-elems per MFMA iteration
#define NITER (DDIM / BK)              // 64
#define TILEB 10240                    // zb tile stride (640 chunks, packed)
#define STRIPES 128                    // 16-row L stripes per k
#define NWG   (KCOMP * STRIPES)        // 1280; %8==0 -> bijective swizzle
#define NXCD  8

typedef __attribute__((ext_vector_type(8))) short bf16x8;  // 8 bf16 = 4 VGPRs
typedef __attribute__((ext_vector_type(4))) short s16x4;   // 4 bf16 = 8 B
typedef __attribute__((ext_vector_type(4))) float f32x4;

__device__ __forceinline__ short bfs(float x) {
    __hip_bfloat16 h = __float2bfloat16(x);   // RNE
    return *reinterpret_cast<short*>(&h);
}

// Kernel 1: counting-bucket the 1024 samples by component (proven v1-v14).
__global__ void build_map(const int* __restrict__ comp,
                          int* __restrict__ rowmap,
                          int* __restrict__ counts) {
    __shared__ int sc[KCOMP];
    const int t = threadIdx.x;
    if (t < KCOMP) sc[t] = 0;
    __syncthreads();
    const int c = comp[t];
    const int r = atomicAdd(&sc[c], 1);
    if (r < MPAD) rowmap[c * MPAD + r] = t;
    __syncthreads();
    if (t < KCOMP) counts[t] = sc[t];
}

// Kernel 2: build the tiled zb image (proven v6-v14, unchanged).
// Block (k, sp) converts slot pair {2sp, 2sp+1}. Thread t, pass p handles
// tile it = p*32 + (t>>3), chunk c = t&7: 8 fp32 of z row (2sp + (c>>2)) at
// d = it*32 + (c&3)*8 -> 16B bf16 at tile + sp*128 + ((c^(sp&7))*16).
__global__ void zgather(const float* __restrict__ z,
                        const int* __restrict__ rowmap,
                        short* __restrict__ zb) {
    const int k  = blockIdx.x;
    const int sp = blockIdx.y;                  // slot pair / macro-row
    const int t  = threadIdx.x;
    const int c  = t & 7;                       // chunk within macro-row
    const int g  = c & 3;
    const int s0 = rowmap[k * MPAD + 2 * sp]     & (BSAMP - 1);
    const int s1 = rowmap[k * MPAD + 2 * sp + 1] & (BSAMP - 1);
    const int src = (c >> 2) ? s1 : s0;
    const int swz = (c ^ (sp & 7)) * 16;        // byte offset within 128B
    char* kbase = (char*)zb + (size_t)k * NITER * TILEB + sp * 128 + swz;
#pragma unroll
    for (int p = 0; p < 2; ++p) {
        const int it = p * 32 + (t >> 3);
        const float* zr = z + (size_t)src * DDIM + it * BK + g * 8;
        f32x4 x = *(const f32x4*)zr;
        f32x4 y = *(const f32x4*)(zr + 4);
        bf16x8 r;
#pragma unroll
        for (int i = 0; i < 4; ++i) { r[i] = bfs(x[i]); r[4 + i] = bfs(y[i]); }
        *(bf16x8*)(kbase + (size_t)it * TILEB) = r;
    }
}

// Kernel 3: grid = 1280 (XCD-swizzled), block = 256 (4 waves).
// Block = (k, stripe): L rows r0..r0+15, ALL d. Stage: 32 coalesced passes
// (4KB/wave-instr) read the 128KB contiguous panel, convert to bf16, write
// LDS row-local with granule swizzle gg' = gg ^ ((row&7)<<1) (8B granules;
// reader's 16B frag = even gg pair stays adjacent under even XOR).
// K-loop (NO barriers; B read-only): per wave, mt tiles {w, w+4, w+8};
// B frag = ds 16B at fr*4096 + ((it*8+2g)^fr2)*8; A frag = direct global
// bf16x8 from zb image (proven v9 addressing), depth-2 reg prefetch.
// C/D col=lane&15 -> e = r0+fr; row = g*4+reg -> slot (m89-verified).
__global__ __launch_bounds__(256, 2)
void gmm_gemm(const short* __restrict__ zb,
              const float* __restrict__ mvec,
              const float* __restrict__ Lmat,
              const int* __restrict__ rowmap,
              const int* __restrict__ counts,
              float* __restrict__ out) {
    __shared__ __attribute__((aligned(16))) short Bs[16 * 2048];   // 64 KB
    char* Bb = (char*)Bs;
    const int t    = threadIdx.x;
    const int lane = t & 63;
    const int w    = t >> 6;          // wave 0..3
    const int lin  = blockIdx.x;
    const int newlin = (lin & (NXCD - 1)) * (NWG / NXCD) + (lin >> 3);
    const int k      = newlin >> 7;   // 128 stripes per k
    const int stripe = newlin & (STRIPES - 1);
    const int r0     = stripe * 16;   // first L row (output col) of block
    const char* zt  = (const char*)zb + (size_t)k * NITER * TILEB;
    const int cnt  = counts[k];

    // ---- stage: 128 KB contiguous -> bf16 LDS (granule-swizzled) ----
    const f32x4* Ls = (const f32x4*)(Lmat + (size_t)k * DDIM * DDIM +
                                     (size_t)r0 * DDIM);
#pragma unroll
    for (int j = 0; j < 32; ++j) {
        const int idx = j * 256 + t;          // 16B chunk 0..8191
        f32x4 v = Ls[idx];
        const int r  = idx >> 9;              // LDS row 0..15
        const int cc = idx & 511;             // granule (4 bf16)
        s16x4 h = (s16x4){bfs(v[0]), bfs(v[1]), bfs(v[2]), bfs(v[3])};
        *(s16x4*)(Bb + r * 4096 + ((cc ^ ((r & 7) << 1)) << 3)) = h;
    }
    __syncthreads();                          // only barrier in the kernel

    // ---- K-loop: barrier-free ----
    const int fr  = lane & 15;        // frag row (L row / out col)
    const int g   = lane >> 4;        // k-group (8 elems)
    const int fr2 = (fr & 7) << 1;
    const int frh = fr >> 1;
    const int fra = (fr & 1) * 4 + g;
    const int abase = frh * 128 + ((fra ^ frh) * 16);   // proven v9 formula

    // wave-uniform per-tile activity (count-aware trim)
    bool act[3];
    const char* ap[3];
#pragma unroll
    for (int i = 0; i < 3; ++i) {
        const int mt = w + 4 * i;
        act[i] = (mt < 10) && (mt * 16 < cnt);
        ap[i]  = zt + mt * 1024 + abase;
    }

    f32x4 acc[3];
#pragma unroll
    for (int i = 0; i < 3; ++i) acc[i] = (f32x4){0.f, 0.f, 0.f, 0.f};

    bf16x8 aE[3], aO[3];
    auto loadA = [&](bf16x8 (&a)[3], int it) {
#pragma unroll
        for (int i = 0; i < 3; ++i)
            if (act[i]) a[i] = *(const bf16x8*)(ap[i] + (size_t)it * TILEB);
    };
    auto step = [&](int it, bf16x8 (&a)[3]) {
        bf16x8 b = *(const bf16x8*)(Bb + fr * 4096 +
                                    (((it * 8 + 2 * g) ^ fr2) << 3));
#pragma unroll
        for (int i = 0; i < 3; ++i)
            if (act[i])
                acc[i] = __builtin_amdgcn_mfma_f32_16x16x32_bf16(a[i], b, acc[i], 0, 0, 0);
    };

    loadA(aE, 0);
    for (int it = 0; it < NITER; it += 2) {
        loadA(aO, it + 1);                    // it+1 <= 63 always
        step(it, aE);
        if (it + 2 < NITER) loadA(aE, it + 2);
        step(it + 1, aO);
    }

    // ---- epilogue ----
    const int e  = r0 + fr;
    const float mu = mvec[k * DDIM + e];
#pragma unroll
    for (int i = 0; i < 3; ++i) {
        if (act[i]) {
            const int sb = (w + 4 * i) * 16 + g * 4;
#pragma unroll
            for (int r = 0; r < 4; ++r) {
                const int slot = sb + r;
                if (slot < cnt) {
                    const int b = rowmap[k * MPAD + slot];
                    out[(size_t)b * DDIM + e] = acc[i][r] + mu;
                }
            }
        }
    }
}

extern "C" void kernel_launch(void* const* d_in, const int* in_sizes, int n_in,
                              void* d_out, int out_size, void* d_ws, size_t ws_size,
                              hipStream_t stream) {
    const float* z    = (const float*)d_in[0];
    const float* mvec = (const float*)d_in[1];
    const float* Lmat = (const float*)d_in[2];
    const int* comp   = (const int*)d_in[3];
    float* out        = (float*)d_out;

    int* rowmap = (int*)d_ws;                         // K*MPAD ints = 6400 B
    int* counts = rowmap + KCOMP * MPAD;              // K ints
    short* zb   = (short*)((char*)d_ws + 8192);       // 6.55 MB packed image

    build_map<<<1, BSAMP, 0, stream>>>(comp, rowmap, counts);
    zgather<<<dim3(KCOMP, MPAD / 2), 256, 0, stream>>>(z, rowmap, zb);
    gmm_gemm<<<NWG, 256, 0, stream>>>(zb, mvec, Lmat, rowmap, counts, out);
}

// Round 16
// 317.578 us; speedup vs baseline: 1.0408x; 1.0408x over previous
//
#include <hip/hip_runtime.h>
#include <hip/hip_bf16.h>

// out[b,e] = m[c,e] + sum_d z[b,d] * L[c,e,d],  c = components[b]
// v16: NT=128 + d-split-4 + atomicAdd merge (the bytes-into-CUs lever).
// Model fitting ALL 15 rounds: kernel time = total bytes moved into CUs
// (any tier) at ~9-13 B/cyc/CU. v5-v12: 587 MB -> 87-103us; v14: 755 -> 97;
// v15: 979 -> 149. Schedule/latency/locality knobs never changed the byte
// total -> all neutral. NT=128 minimizes bytes (A 105 + B 168 = 273 MB) but
// v11's 160 blocks stranded 96 CUs -> d-split-4 gives 640 balanced blocks
// with the SAME byte total. Merge = native fp32 atomicAdd to out (coalesced,
// ~34 MB RMW), out pre-zeroed inside the existing zgather launch (no new
// node), mu folded into split 0. All maps proven-verbatim from v6-v14.

#define DDIM  2048
#define BSAMP 1024
#define KCOMP 10
#define MPAD  160                      // max n_k pad; Binom(1024,0.1)+6sigma
#define NT    128                      // block N tile
#define BK    32                       // d-elems per iteration
#define SPLITS 4
#define NS    16                       // iterations per block (512/BK)
#define TILEB 10240                    // zb tile stride (640 chunks, packed)
#define ALDS  12288                    // A LDS region (640 real + pad)
#define BLDS  16384                    // B LDS region (128 rows x 128B)
#define STAGE_BYTES (ALDS + BLDS)      // 28672; x2 = 57344 -> 2 blocks/CU
#define NWG   (KCOMP * 16 * SPLITS)    // 640 blocks

typedef __attribute__((ext_vector_type(8))) short bf16x8;  // 8 bf16 = 4 VGPRs
typedef __attribute__((ext_vector_type(4))) float f32x4;

__device__ __forceinline__ void async16(void* lds, const void* g) {
    __builtin_amdgcn_global_load_lds(
        (const __attribute__((address_space(1))) void*)g,
        (__attribute__((address_space(3))) void*)lds, 16, 0, 0);
}

__device__ __forceinline__ short bfs(float x) {
    __hip_bfloat16 h = __float2bfloat16(x);   // RNE
    return *reinterpret_cast<short*>(&h);
}

// Kernel 1: counting-bucket the 1024 samples by component (proven v1-v15).
__global__ void build_map(const int* __restrict__ comp,
                          int* __restrict__ rowmap,
                          int* __restrict__ counts) {
    __shared__ int sc[KCOMP];
    const int t = threadIdx.x;
    if (t < KCOMP) sc[t] = 0;
    __syncthreads();
    const int c = comp[t];
    const int r = atomicAdd(&sc[c], 1);
    if (r < MPAD) rowmap[c * MPAD + r] = t;
    __syncthreads();
    if (t < KCOMP) counts[t] = sc[t];
}

// Kernel 2: build the tiled zb image (proven v6-v15) + zero `out` for the
// atomic merge (zid < 512 blocks each zero 4096 floats; 512*4096 = 2^21 =
// exactly BSAMP*DDIM). No extra launch node.
__global__ void zgather(const float* __restrict__ z,
                        const int* __restrict__ rowmap,
                        short* __restrict__ zb,
                        float* __restrict__ out) {
    const int k  = blockIdx.x;
    const int sp = blockIdx.y;                  // slot pair / macro-row
    const int t  = threadIdx.x;
    const int zid = k * (MPAD / 2) + sp;        // 0..799
    if (zid < 512) {
        float* o = out + (size_t)zid * 4096;
        const f32x4 zero = (f32x4){0.f, 0.f, 0.f, 0.f};
#pragma unroll
        for (int j = 0; j < 4; ++j)
            *(f32x4*)(o + (j * 256 + t) * 4) = zero;
    }
    const int c  = t & 7;                       // chunk within macro-row
    const int g  = c & 3;
    const int s0 = rowmap[k * MPAD + 2 * sp]     & (BSAMP - 1);
    const int s1 = rowmap[k * MPAD + 2 * sp + 1] & (BSAMP - 1);
    const int src = (c >> 2) ? s1 : s0;
    const int swz = (c ^ (sp & 7)) * 16;        // byte offset within 128B
    char* kbase = (char*)zb + (size_t)k * 64 * TILEB + sp * 128 + swz;
#pragma unroll
    for (int p = 0; p < 2; ++p) {
        const int it = p * 32 + (t >> 3);
        const float* zr = z + (size_t)src * DDIM + it * BK + g * 8;
        f32x4 x = *(const f32x4*)zr;
        f32x4 y = *(const f32x4*)(zr + 4);
        bf16x8 r;
#pragma unroll
        for (int i = 0; i < 4; ++i) { r[i] = bfs(x[i]); r[4 + i] = bfs(y[i]); }
        *(bf16x8*)(kbase + (size_t)it * TILEB) = r;
    }
}

// Kernel 3: grid = 640 (1D), block = 256 (4 waves).
// bid -> s = bid&3 (d-split), ntile = (bid>>2)&15, k = bid>>6.
// Block tile 160x128 over d in [s*512, s*512+512); wave tile 80x64
// (mh = w>>1, nh = w&1; 4 n-subtiles q). acc[5][4]. v6 sync structure.
// A stage: 640 chunks, ops t / 256+t / clamp(512+t,639) (v11-proven).
// B stage: 1024 chunks (row = c>>3, h = (c&7)^(r&7)), 4 uniform ops.
// A frag: abase + mt*1024 (proven; mh*40, mt*8 == 0 mod 8). B frag: row
// rb = nh*64 + q*16 + fr; rb&7 = fr&7 -> h0/h1 q-independent (proven map).
// Epilogue: atomicAdd(out) with mu folded into split 0.
__global__ __launch_bounds__(256, 2)
void gmm_gemm(const short* __restrict__ zb,
              const float* __restrict__ mvec,
              const float* __restrict__ Lmat,
              const int* __restrict__ rowmap,
              const int* __restrict__ counts,
              float* __restrict__ out) {
    __shared__ __attribute__((aligned(16))) char smem[2 * STAGE_BYTES];
    const int t    = threadIdx.x;
    const int lane = t & 63;
    const int w    = t >> 6;
    const int mh   = w >> 1;          // wave M-half (80 rows)
    const int nh   = w & 1;           // wave N-half (64 cols)
    const int bid  = blockIdx.x;
    const int s    = bid & 3;                    // d-split
    const int n0   = ((bid >> 2) & 15) * NT;
    const int k    = bid >> 6;
    const int ts   = s * NS;                     // first zb tile of this split
    const int d0b  = s * 512;                    // first d of this split
    const float* Lk = Lmat + (size_t)k * DDIM * DDIM;
    const char* zt  = (const char*)zb + (size_t)k * 64 * TILEB;
    const int cnt  = counts[k];

    // count-aware trim: this wave's rows are mh*80 + mt*16 + {0..15}
    int mtmax = (cnt - mh * 80 + 15) >> 4;
    mtmax = mtmax < 0 ? 0 : (mtmax > 5 ? 5 : mtmax);

    // A staging: 640 chunks, op2 clamp-dups into pad (v11-proven)
    const int ac2 = (512 + t < 640) ? (512 + t) : 639;
    // B staging: 1024 chunks over 4 ops
    int brr[4], bcc[4];
#pragma unroll
    for (int j = 0; j < 4; ++j) {
        const int c = j * 256 + t;
        brr[j] = c >> 3;
        bcc[j] = (((c & 7) ^ (brr[j] & 7)) * 4);
    }
    const unsigned ub = (unsigned)(t & ~63) * 16;   // wave-uniform byte base

    auto stage = [&](int buf, int it) {             // 7 uniform ops/thread
        char* lb = smem + buf * STAGE_BYTES;
        const char* at = zt + (size_t)(ts + it) * TILEB;
        async16(lb + ub,        at + t * 16);
        async16(lb + 4096 + ub, at + 4096 + t * 16);
        async16(lb + 8192 + ub, at + ac2 * 16);
        const int d0 = d0b + it * BK;
#pragma unroll
        for (int j = 0; j < 4; ++j)
            async16(lb + ALDS + j * 4096 + ub,
                    Lk + (size_t)(n0 + brr[j]) * DDIM + d0 + bcc[j]);
    };

    f32x4 acc[5][4];
#pragma unroll
    for (int mt = 0; mt < 5; ++mt)
#pragma unroll
        for (int q = 0; q < 4; ++q) acc[mt][q] = (f32x4){0.f, 0.f, 0.f, 0.f};

    stage(0, 0);
    __syncthreads();                 // drains vmcnt -> buf0 ready

    const int fr = lane & 15;        // frag row
    const int g  = lane >> 4;        // k-group (8 elems) of this lane
    const int h0 = ((2 * g)     ^ (fr & 7)) * 4;   // rb&7 == fr&7 for all q
    const int h1 = ((2 * g + 1) ^ (fr & 7)) * 4;
    const int frh = fr >> 1;
    const int fra = (fr & 1) * 4 + g;
    const int abase = (mh * 40 + frh) * 128 + ((fra ^ frh) * 16);

    for (int it = 0; it < NS; ++it) {
        if (it + 1 < NS) stage((it + 1) & 1, it + 1);
        const char* lb = smem + (it & 1) * STAGE_BYTES;
        const float* B = (const float*)(lb + ALDS);

        bf16x8 bb[4];
#pragma unroll
        for (int q = 0; q < 4; ++q) {
            const int rb = nh * 64 + q * 16 + fr;
            f32x4 x = *(const f32x4*)(B + rb * 32 + h0);
            f32x4 y = *(const f32x4*)(B + rb * 32 + h1);
#pragma unroll
            for (int i = 0; i < 4; ++i) {
                bb[q][i]     = bfs(x[i]);
                bb[q][4 + i] = bfs(y[i]);
            }
        }
#pragma unroll
        for (int mt = 0; mt < 5; ++mt) {
            if (mt < mtmax) {        // wave-uniform guard, static acc index
                bf16x8 a = *(const bf16x8*)(lb + abase + mt * 1024);
#pragma unroll
                for (int q = 0; q < 4; ++q)
                    acc[mt][q] = __builtin_amdgcn_mfma_f32_16x16x32_bf16(a, bb[q], acc[mt][q], 0, 0, 0);
            }
        }
        __syncthreads();             // cur buf consumed; prefetch drained
    }

    // epilogue: C/D layout col=lane&15, row=(lane>>4)*4+reg (m89-verified).
    // atomicAdd merge; mu added exactly once (split 0).
    const int rquad = g * 4;
#pragma unroll
    for (int q = 0; q < 4; ++q) {
        const int e = n0 + nh * 64 + q * 16 + fr;
        const float mu = (s == 0) ? mvec[k * DDIM + e] : 0.f;
#pragma unroll
        for (int mt = 0; mt < 5; ++mt) {
            if (mt < mtmax) {
                const int sb = mh * 80 + mt * 16 + rquad;
#pragma unroll
                for (int r = 0; r < 4; ++r) {
                    const int slot = sb + r;
                    if (slot < cnt) {
                        const int b = rowmap[k * MPAD + slot];
                        atomicAdd(&out[(size_t)b * DDIM + e],
                                  acc[mt][q][r] + mu);
                    }
                }
            }
        }
    }
}

extern "C" void kernel_launch(void* const* d_in, const int* in_sizes, int n_in,
                              void* d_out, int out_size, void* d_ws, size_t ws_size,
                              hipStream_t stream) {
    const float* z    = (const float*)d_in[0];
    const float* mvec = (const float*)d_in[1];
    const float* Lmat = (const float*)d_in[2];
    const int* comp   = (const int*)d_in[3];
    float* out        = (float*)d_out;

    int* rowmap = (int*)d_ws;                         // K*MPAD ints = 6400 B
    int* counts = rowmap + KCOMP * MPAD;              // K ints
    short* zb   = (short*)((char*)d_ws + 8192);       // 6.55 MB packed image

    build_map<<<1, BSAMP, 0, stream>>>(comp, rowmap, counts);
    zgather<<<dim3(KCOMP, MPAD / 2), 256, 0, stream>>>(z, rowmap, zb, out);
    gmm_gemm<<<NWG, 256, 0, stream>>>(zb, mvec, Lmat, rowmap, counts, out);
}